// Round 10
// baseline (418.151 us; speedup 1.0000x reference)
//
#include <hip/hip_runtime.h>
#include <math.h>

#define NN   50000
#define EE   600000
#define CCH  128
#define HH   8
#define DD   16
#define OUTC 16
#define NEG  0.2f
#define EPSN 1e-5f
#define SLICE_DIV 12500   // 2*NN / 8 slices

typedef _Float16 f16x8 __attribute__((ext_vector_type(8)));
typedef float    f32x4 __attribute__((ext_vector_type(4)));

__device__ __forceinline__ float fast_tanh(float x) {
    x = fminf(10.f, fmaxf(-10.f, x));
    float e = __expf(2.f * x);
    return (e - 1.f) / (e + 1.f);
}

// ---------- prep: weight transpose+convert (4 mats) + XCD-sharded degree histogram ----------
__global__ __launch_bounds__(256) void prep_k(const float* __restrict__ W_a,
        const float* __restrict__ W_p, const float* __restrict__ k_W,
        const float* __restrict__ lin_W, const int* __restrict__ ea,
        const int* __restrict__ ep, _Float16* __restrict__ Wt_a,
        _Float16* __restrict__ Wt_p, _Float16* __restrict__ kWt,
        _Float16* __restrict__ linWt, int* __restrict__ counts)
{
    int b = blockIdx.x;
    if (b < 264) {
        int id = b * 256 + threadIdx.x;
        if (id < 32768) {
            int k = id >> 7, n = id & 127;
            Wt_a[n * 256 + k] = (_Float16)W_a[id];
        } else if (id < 49152) {
            int i = id - 32768; int k = i >> 7, n = i & 127;
            Wt_p[n * 128 + k] = (_Float16)W_p[i];
        } else if (id < 65536) {
            int i = id - 49152; int k = i >> 7, n = i & 127;
            kWt[n * 128 + k] = (_Float16)k_W[i];
        } else if (id < 67584) {
            int i = id - 65536; int k = i >> 4, n = i & 15;
            linWt[n * 128 + k] = (_Float16)lin_W[i];
        }
    } else {
        int bb = b - 264;
        int slice = bb & 7;
        int chunk = bb >> 3;
        int lo = slice * SLICE_DIV, hi = lo + SLICE_DIV;
        int base = chunk * 1024;
#pragma unroll
        for (int it = 0; it < 4; ++it) {
            int e = base + it * 256 + threadIdx.x;
            if (e < EE) {
                int d = ea[EE + e];
                if (d >= lo && d < hi) atomicAdd(&counts[d], 1);
            } else if (e < 2 * EE) {
                int d = NN + ep[e];
                if (d >= lo && d < hi) atomicAdd(&counts[d], 1);
            }
        }
    }
}

// ---------- LDS-free GEMM accumulate: A direct from fp32 global (in-reg cvt), B from L2-hot Wt ----------
template<int K>
__device__ __forceinline__ void gemm_acc(const float* __restrict__ X,
        const _Float16* __restrict__ Wt, int rowbase, int m16, int kq, f32x4 acc[8])
{
    constexpr int NC = K / 32;
    const int arow = rowbase + m16;
    f16x8 af[NC];
    if (arow < NN) {
#pragma unroll
        for (int c = 0; c < NC; ++c) {
            const float4* gp = (const float4*)&X[arow * K + c * 32 + kq * 8];
            float4 x0 = gp[0], x1 = gp[1];
            f16x8 v;
            v[0] = (_Float16)x0.x; v[1] = (_Float16)x0.y;
            v[2] = (_Float16)x0.z; v[3] = (_Float16)x0.w;
            v[4] = (_Float16)x1.x; v[5] = (_Float16)x1.y;
            v[6] = (_Float16)x1.z; v[7] = (_Float16)x1.w;
            af[c] = v;
        }
    } else {
#pragma unroll
        for (int c = 0; c < NC; ++c)
#pragma unroll
            for (int j = 0; j < 8; ++j) af[c][j] = (_Float16)0.f;
    }
#pragma unroll
    for (int c = 0; c < NC; ++c) {
#pragma unroll
        for (int i = 0; i < 8; ++i) {
            f16x8 bf = *(const f16x8*)&Wt[(i * 16 + m16) * K + c * 32 + kq * 8];
            acc[i] = __builtin_amdgcn_mfma_f32_16x16x32_f16(af[c], bf, acc[i], 0, 0, 0);
        }
    }
}

// ---------------- both projections + alpha logits, zero LDS / zero barriers ----------------
__global__ __launch_bounds__(256) void gemm2_k(const float* __restrict__ X_a,
        const float* __restrict__ X_p, const _Float16* __restrict__ Wt_a,
        const _Float16* __restrict__ Wt_p, const float* __restrict__ b_a,
        const float* __restrict__ b_p,
        const float* __restrict__ att_s_ap, const float* __restrict__ att_d_ap,
        const float* __restrict__ att_s_pp, const float* __restrict__ att_d_pp,
        _Float16* __restrict__ h_a, _Float16* __restrict__ h_p,
        float* __restrict__ as_ap, float* __restrict__ ad_ap,
        float* __restrict__ as_pp, float* __restrict__ ad_pp, int GBn)
{
    const int which = ((int)blockIdx.x >= GBn) ? 1 : 0;
    const float* bias = which ? b_p : b_a;
    _Float16* Y = which ? h_p : h_a;
    const int t = threadIdx.x;
    const int r0 = (blockIdx.x - which * GBn) * 64;
    const int lane = t & 63;
    const int wv = t >> 6;
    const int m16 = lane & 15;
    const int kq = lane >> 4;
    f32x4 acc[8];
#pragma unroll
    for (int i = 0; i < 8; ++i) acc[i] = (f32x4){0.f, 0.f, 0.f, 0.f};

    if (which == 0) gemm_acc<256>(X_a, Wt_a, r0 + wv * 16, m16, kq, acc);
    else            gemm_acc<128>(X_p, Wt_p, r0 + wv * 16, m16, kq, acc);

    const int rbase = r0 + wv * 16 + kq * 4;
#pragma unroll
    for (int i = 0; i < 8; ++i) {
        int col = i * 16 + m16;
        float b = bias[col];
        float hv[4];
#pragma unroll
        for (int rr = 0; rr < 4; ++rr) hv[rr] = acc[i][rr] + b;
#pragma unroll
        for (int rr = 0; rr < 4; ++rr)
            if (rbase + rr < NN) Y[(rbase + rr) * 128 + col] = (_Float16)hv[rr];
        if (which == 0) {
            float av = att_s_ap[i * 16 + m16];
            float p[4];
#pragma unroll
            for (int rr = 0; rr < 4; ++rr) p[rr] = hv[rr] * av;
#pragma unroll
            for (int x = 1; x < 16; x <<= 1)
#pragma unroll
                for (int rr = 0; rr < 4; ++rr) p[rr] += __shfl_xor(p[rr], x, 64);
            if (m16 == 0) {
#pragma unroll
                for (int rr = 0; rr < 4; ++rr)
                    if (rbase + rr < NN) as_ap[(rbase + rr) * 8 + i] = p[rr];
            }
        } else {
            float a1 = att_d_ap[i * 16 + m16];
            float a2 = att_s_pp[i * 16 + m16];
            float a3 = att_d_pp[i * 16 + m16];
            float p1[4], p2[4], p3[4];
#pragma unroll
            for (int rr = 0; rr < 4; ++rr) {
                p1[rr] = hv[rr] * a1; p2[rr] = hv[rr] * a2; p3[rr] = hv[rr] * a3;
            }
#pragma unroll
            for (int x = 1; x < 16; x <<= 1) {
#pragma unroll
                for (int rr = 0; rr < 4; ++rr) {
                    p1[rr] += __shfl_xor(p1[rr], x, 64);
                    p2[rr] += __shfl_xor(p2[rr], x, 64);
                    p3[rr] += __shfl_xor(p3[rr], x, 64);
                }
            }
            if (m16 == 0) {
#pragma unroll
                for (int rr = 0; rr < 4; ++rr) {
                    if (rbase + rr < NN) {
                        ad_ap[(rbase + rr) * 8 + i] = p1[rr];
                        as_pp[(rbase + rr) * 8 + i] = p2[rr];
                        ad_pp[(rbase + rr) * 8 + i] = p3[rr];
                    }
                }
            }
        }
    }
}

// ---------- scans for CSR row pointers (100000 segments) ----------
__global__ __launch_bounds__(256) void scan1_k(const int* __restrict__ counts,
        int* __restrict__ incl, int* __restrict__ bsum) {
    __shared__ int s[256];
    int t = threadIdx.x;
    int i = blockIdx.x * 256 + t;
    int v = (i < 2 * NN) ? counts[i] : 0;
    s[t] = v; __syncthreads();
    for (int off = 1; off < 256; off <<= 1) {
        int x = (t >= off) ? s[t - off] : 0;
        __syncthreads();
        s[t] += x;
        __syncthreads();
    }
    incl[i] = s[t];
    if (t == 255) bsum[blockIdx.x] = s[255];
}

__global__ __launch_bounds__(512) void scan2_k(int* __restrict__ bsum, int nb) {
    __shared__ int s[512];
    int t = threadIdx.x;
    int v = (t < nb) ? bsum[t] : 0;
    s[t] = v; __syncthreads();
    for (int off = 1; off < 512; off <<= 1) {
        int x = (t >= off) ? s[t - off] : 0;
        __syncthreads();
        s[t] += x;
        __syncthreads();
    }
    if (t < nb) bsum[t] = s[t] - v;   // exclusive
}

__global__ __launch_bounds__(256) void scan3_k(const int* __restrict__ incl,
        const int* __restrict__ bexcl, int* __restrict__ rp) {
    int i = blockIdx.x * 256 + threadIdx.x;
    if (i < 2 * NN) rp[i + 1] = incl[i] + bexcl[blockIdx.x];
    if (i == 0) rp[0] = 0;
}

// ---------- XCD-sharded CSR scatter ----------
__global__ __launch_bounds__(256) void scat_k(const int* __restrict__ ea,
        const int* __restrict__ ep, const int* __restrict__ rp,
        int* __restrict__ fill, int* __restrict__ csr)
{
    int bb = blockIdx.x;
    int slice = bb & 7;
    int chunk = bb >> 3;
    int lo = slice * SLICE_DIV, hi = lo + SLICE_DIV;
    int base = chunk * 1024;
#pragma unroll
    for (int it = 0; it < 4; ++it) {
        int e = base + it * 256 + threadIdx.x;
        if (e < EE) {
            int d = ea[EE + e];
            if (d >= lo && d < hi) {
                int pos = rp[d] + atomicAdd(&fill[d], 1);
                csr[pos] = ea[e];
            }
        } else if (e < 2 * EE) {
            int d = NN + ep[e];
            if (d >= lo && d < hi) {
                int pos = rp[d] + atomicAdd(&fill[d], 1);
                csr[pos] = ep[e - EE];
            }
        }
    }
}

// ---------- aggregation: 4 nodes/wave, 16 lanes (f16x8)/node, inline l, unroll x4 ----------
__global__ __launch_bounds__(256) void agg4_k(
        const _Float16* __restrict__ h_a, const _Float16* __restrict__ h_p,
        const float* __restrict__ as_ap, const float* __restrict__ ad_ap,
        const float* __restrict__ as_pp, const float* __restrict__ ad_pp,
        const int* __restrict__ rp, const int* __restrict__ csr,
        _Float16* __restrict__ out_ap, _Float16* __restrict__ out_pp)
{
    int wave = threadIdx.x >> 6;
    int lane = threadIdx.x & 63;
    int q = lane >> 4;                 // node slot within wave
    int sub = lane & 15;               // 8-channel group: c0 = sub*8
    int gnode = blockIdx.x * 16 + wave * 4 + q;
    bool pp = gnode >= NN;
    int n = pp ? gnode - NN : gnode;
    const _Float16* hsrc = pp ? h_p : h_a;
    const float* as = pp ? as_pp : as_ap;
    const float* ad = pp ? ad_pp : ad_ap;
    _Float16* outb = pp ? out_pp : out_ap;
    int h = sub >> 1;                  // head of this channel group
    float adv = ad[n * 8 + h];
    int p = rp[gnode], p1 = rp[gnode + 1];
    float l = 0.f;
    float acc[8] = {0.f, 0.f, 0.f, 0.f, 0.f, 0.f, 0.f, 0.f};
    for (; p + 3 < p1; p += 4) {
        int s0 = csr[p], s1 = csr[p + 1], s2 = csr[p + 2], s3 = csr[p + 3];
        float a0 = as[s0 * 8 + h] + adv;
        float a1 = as[s1 * 8 + h] + adv;
        float a2 = as[s2 * 8 + h] + adv;
        float a3 = as[s3 * 8 + h] + adv;
        a0 = (a0 >= 0.f) ? a0 : NEG * a0;
        a1 = (a1 >= 0.f) ? a1 : NEG * a1;
        a2 = (a2 >= 0.f) ? a2 : NEG * a2;
        a3 = (a3 >= 0.f) ? a3 : NEG * a3;
        float w0 = __expf(a0), w1 = __expf(a1), w2 = __expf(a2), w3 = __expf(a3);
        f16x8 v0 = *(const f16x8*)&hsrc[s0 * CCH + sub * 8];
        f16x8 v1 = *(const f16x8*)&hsrc[s1 * CCH + sub * 8];
        f16x8 v2 = *(const f16x8*)&hsrc[s2 * CCH + sub * 8];
        f16x8 v3 = *(const f16x8*)&hsrc[s3 * CCH + sub * 8];
        l += (w0 + w1) + (w2 + w3);
#pragma unroll
        for (int i = 0; i < 8; ++i)
            acc[i] += (w0 * (float)v0[i] + w1 * (float)v1[i])
                    + (w2 * (float)v2[i] + w3 * (float)v3[i]);
    }
    for (; p < p1; ++p) {
        int s0 = csr[p];
        float a0 = as[s0 * 8 + h] + adv;
        a0 = (a0 >= 0.f) ? a0 : NEG * a0;
        float w0 = __expf(a0);
        f16x8 v0 = *(const f16x8*)&hsrc[s0 * CCH + sub * 8];
        l += w0;
#pragma unroll
        for (int i = 0; i < 8; ++i) acc[i] += w0 * (float)v0[i];
    }
    float inv = (l > 0.f) ? 1.f / l : 0.f;
    f16x8 o;
#pragma unroll
    for (int i = 0; i < 8; ++i) o[i] = (_Float16)fmaxf(acc[i] * inv, 0.f);
    *(f16x8*)&outb[n * CCH + sub * 8] = o;
}

// ---------- fused: blocks 0..255 channel stats; rest LDS-free sem GEMM ----------
__global__ __launch_bounds__(256) void semstats2_k(const _Float16* __restrict__ Xa,
        const _Float16* __restrict__ Xb, const _Float16* __restrict__ kWt,
        const float* __restrict__ kb, const float* __restrict__ q,
        float* __restrict__ wacc, float* __restrict__ sA, float* __restrict__ sB,
        float* __restrict__ ssA, float* __restrict__ ssB, float* __restrict__ sAB,
        int GBn)
{
    __shared__ float sbuf[640];
    const int t = threadIdx.x;
    if ((int)blockIdx.x < 256) {
        for (int i = t; i < 640; i += 256) sbuf[i] = 0.f;
        __syncthreads();
        int oct = t & 15, rs = t >> 4;
        int start = (int)blockIdx.x * 196;
        int end = start + 196; if (end > NN) end = NN;
        float sa[8] = {0,0,0,0,0,0,0,0}, sb[8] = {0,0,0,0,0,0,0,0};
        float ssa[8] = {0,0,0,0,0,0,0,0}, ssb[8] = {0,0,0,0,0,0,0,0};
        float sab[8] = {0,0,0,0,0,0,0,0};
        for (int r = start + rs; r < end; r += 16) {
            f16x8 va = *(const f16x8*)&Xa[r * 128 + oct * 8];
            f16x8 vb = *(const f16x8*)&Xb[r * 128 + oct * 8];
#pragma unroll
            for (int j = 0; j < 8; ++j) {
                float a = (float)va[j], b = (float)vb[j];
                sa[j] += a; sb[j] += b;
                ssa[j] += a * a; ssb[j] += b * b; sab[j] += a * b;
            }
        }
#pragma unroll
        for (int x = 16; x < 64; x <<= 1) {
#pragma unroll
            for (int j = 0; j < 8; ++j) {
                sa[j]  += __shfl_xor(sa[j],  x, 64);
                sb[j]  += __shfl_xor(sb[j],  x, 64);
                ssa[j] += __shfl_xor(ssa[j], x, 64);
                ssb[j] += __shfl_xor(ssb[j], x, 64);
                sab[j] += __shfl_xor(sab[j], x, 64);
            }
        }
        if ((t & 63) < 16) {
            int c0 = oct * 8;
#pragma unroll
            for (int j = 0; j < 8; ++j) {
                atomicAdd(&sbuf[c0 + j], sa[j]);
                atomicAdd(&sbuf[128 + c0 + j], sb[j]);
                atomicAdd(&sbuf[256 + c0 + j], ssa[j]);
                atomicAdd(&sbuf[384 + c0 + j], ssb[j]);
                atomicAdd(&sbuf[512 + c0 + j], sab[j]);
            }
        }
        __syncthreads();
        if (t < 128) {
            atomicAdd(&sA[t],  sbuf[t]);
            atomicAdd(&sB[t],  sbuf[128 + t]);
            atomicAdd(&ssA[t], sbuf[256 + t]);
            atomicAdd(&ssB[t], sbuf[384 + t]);
            atomicAdd(&sAB[t], sbuf[512 + t]);
        }
    } else {
        const int b = (int)blockIdx.x - 256;
        const int which = (b >= GBn) ? 1 : 0;
        const _Float16* Xh = which ? Xb : Xa;
        const int r0 = (b - which * GBn) * 64;
        const int lane = t & 63, wv = t >> 6;
        const int m16 = lane & 15, kq = lane >> 4;
        const int arow = r0 + wv * 16 + m16;
        f16x8 af[4];
        if (arow < NN) {
#pragma unroll
            for (int kc4 = 0; kc4 < 4; ++kc4)
                af[kc4] = *(const f16x8*)&Xh[arow * 128 + kc4 * 32 + kq * 8];
        } else {
#pragma unroll
            for (int kc4 = 0; kc4 < 4; ++kc4)
#pragma unroll
                for (int j = 0; j < 8; ++j) af[kc4][j] = (_Float16)0.f;
        }
        f32x4 acc[8];
#pragma unroll
        for (int i = 0; i < 8; ++i) acc[i] = (f32x4){0.f, 0.f, 0.f, 0.f};
#pragma unroll
        for (int kc4 = 0; kc4 < 4; ++kc4) {
#pragma unroll
            for (int i = 0; i < 8; ++i) {
                f16x8 bf = *(const f16x8*)&kWt[(i * 16 + m16) * 128 + kc4 * 32 + kq * 8];
                acc[i] = __builtin_amdgcn_mfma_f32_16x16x32_f16(af[kc4], bf, acc[i], 0, 0, 0);
            }
        }
        const int rbase = r0 + wv * 16 + kq * 4;
        float local = 0.f;
#pragma unroll
        for (int i = 0; i < 8; ++i) {
            float kbc = kb[i * 16 + m16], qc = q[i * 16 + m16];
#pragma unroll
            for (int rr = 0; rr < 4; ++rr)
                if (rbase + rr < NN) local += fast_tanh(acc[i][rr] + kbc) * qc;
        }
#pragma unroll
        for (int x = 1; x < 64; x <<= 1) local += __shfl_xor(local, x, 64);
        if (lane == 0) sbuf[wv] = local;
        __syncthreads();
        if (t == 0) {
            float s = sbuf[0] + sbuf[1] + sbuf[2] + sbuf[3];
            atomicAdd(&wacc[which * 256 + (b & 15) * 16], s);
        }
    }
}

// ---------- GraphNorm (inline beta, sums 16 buckets/path) + final 128->16 linear via MFMA ----------
__global__ __launch_bounds__(256) void final2_k(
        const _Float16* __restrict__ oa, const _Float16* __restrict__ ob,
        const float* __restrict__ wacc,
        const float* __restrict__ sA, const float* __restrict__ sB,
        const float* __restrict__ ssA, const float* __restrict__ ssB,
        const float* __restrict__ sAB,
        const float* __restrict__ ms, const float* __restrict__ nw,
        const float* __restrict__ nb,
        const _Float16* __restrict__ linWt, const float* __restrict__ linb,
        float* __restrict__ out)
{
    __shared__ _Float16 As[64][136];
    __shared__ float scl[128], shf[128];
    __shared__ float bcoef[2];
    int t = threadIdx.x;
    if (t < 128) {
        float w0s = 0.f, w1s = 0.f;
#pragma unroll
        for (int i = 0; i < 16; ++i) {
            w0s += wacc[i * 16];
            w1s += wacc[256 + i * 16];
        }
        float w0 = w0s * (1.f / NN), w1 = w1s * (1.f / NN);
        float mm = fmaxf(w0, w1);
        float e0 = __expf(w0 - mm), e1 = __expf(w1 - mm);
        float b0 = e0 / (e0 + e1), b1 = e1 / (e0 + e1);
        if (t == 0) { bcoef[0] = b0; bcoef[1] = b1; }
        int c = t;
        float mean = (b0 * sA[c] + b1 * sB[c]) * (1.f / NN);
        float ex2 = (b0 * b0 * ssA[c] + 2.f * b0 * b1 * sAB[c] + b1 * b1 * ssB[c]) * (1.f / NN);
        float a = mean * ms[c];
        float var = ex2 - 2.f * a * mean + a * a;
        float sc = nw[c] * rsqrtf(var + EPSN);
        scl[c] = sc;
        shf[c] = nb[c] - a * sc;
    }
    __syncthreads();
    float b0 = bcoef[0], b1 = bcoef[1];
    int r0 = blockIdx.x * 64;
    int row = t >> 2, cp = (t & 3) * 32;
    int gr = r0 + row;
    if (gr < NN) {
#pragma unroll
        for (int i = 0; i < 4; ++i) {
            int c0 = cp + i * 8;
            f16x8 va = *(const f16x8*)&oa[gr * CCH + c0];
            f16x8 vb = *(const f16x8*)&ob[gr * CCH + c0];
            f16x8 o;
#pragma unroll
            for (int e2 = 0; e2 < 8; ++e2) {
                float v = b0 * (float)va[e2] + b1 * (float)vb[e2];
                o[e2] = (_Float16)(v * scl[c0 + e2] + shf[c0 + e2]);
            }
            *(f16x8*)&As[row][c0] = o;
        }
    } else {
        f16x8 z;
#pragma unroll
        for (int e2 = 0; e2 < 8; ++e2) z[e2] = (_Float16)0.f;
#pragma unroll
        for (int i = 0; i < 4; ++i) *(f16x8*)&As[row][cp + i * 8] = z;
    }
    __syncthreads();
    int lane = t & 63, wv = t >> 6;
    int m16 = lane & 15, kq = lane >> 4;
    f32x4 acc = (f32x4){0.f, 0.f, 0.f, 0.f};
#pragma unroll
    for (int kc = 0; kc < 128; kc += 32) {
        f16x8 af = *(const f16x8*)&As[wv * 16 + m16][kc + kq * 8];
        f16x8 bf = *(const f16x8*)&linWt[m16 * 128 + kc + kq * 8];
        acc = __builtin_amdgcn_mfma_f32_16x16x32_f16(af, bf, acc, 0, 0, 0);
    }
    float lb = linb[m16];
#pragma unroll
    for (int r = 0; r < 4; ++r) {
        int gr2 = r0 + wv * 16 + kq * 4 + r;
        if (gr2 < NN) out[gr2 * 16 + m16] = acc[r] + lb;
    }
}

extern "C" void kernel_launch(void* const* d_in, const int* in_sizes, int n_in,
                              void* d_out, int out_size, void* d_ws, size_t ws_size,
                              hipStream_t stream) {
    const float* x_a   = (const float*)d_in[0];
    const float* x_p   = (const float*)d_in[1];
    const float* W_a   = (const float*)d_in[2];
    const float* b_a   = (const float*)d_in[3];
    const float* W_p   = (const float*)d_in[4];
    const float* b_p   = (const float*)d_in[5];
    const float* att_src_ap = (const float*)d_in[6];
    const float* att_dst_ap = (const float*)d_in[7];
    const float* att_src_pp = (const float*)d_in[8];
    const float* att_dst_pp = (const float*)d_in[9];
    const float* k_W   = (const float*)d_in[10];
    const float* k_b   = (const float*)d_in[11];
    const float* q     = (const float*)d_in[12];
    const float* norm_w = (const float*)d_in[13];
    const float* norm_b = (const float*)d_in[14];
    const float* norm_ms = (const float*)d_in[15];
    const float* lin_W = (const float*)d_in[16];
    const float* lin_b = (const float*)d_in[17];
    const int* edge_ap = (const int*)d_in[18];
    const int* edge_pp = (const int*)d_in[19];
    float* out = (float*)d_out;

    char* base = (char*)d_ws;
    size_t off = 0;
    auto alloc = [&](size_t bytes) -> void* {
        void* r = base + off;
        off += (bytes + 255) & ~(size_t)255;
        return r;
    };
    _Float16* h_a    = (_Float16*)alloc((size_t)NN * CCH * 2);
    _Float16* h_p    = (_Float16*)alloc((size_t)NN * CCH * 2);
    _Float16* out_ap = (_Float16*)alloc((size_t)NN * CCH * 2);
    _Float16* out_pp = (_Float16*)alloc((size_t)NN * CCH * 2);
    float* as_ap  = (float*)alloc((size_t)NN * HH * 4);
    float* ad_ap  = (float*)alloc((size_t)NN * HH * 4);
    float* as_pp  = (float*)alloc((size_t)NN * HH * 4);
    float* ad_pp  = (float*)alloc((size_t)NN * HH * 4);
    _Float16* Wt_a = (_Float16*)alloc((size_t)128 * 256 * 2);
    _Float16* Wt_p = (_Float16*)alloc((size_t)128 * 128 * 2);
    _Float16* kWt  = (_Float16*)alloc((size_t)128 * 128 * 2);
    _Float16* linWt = (_Float16*)alloc((size_t)16 * 128 * 2);
    int* incl    = (int*)alloc((size_t)100352 * 4);
    int* bsum    = (int*)alloc(512 * 4);
    int* rp_all  = (int*)alloc((size_t)(2 * NN + 1) * 4);
    int* csr_all = (int*)alloc((size_t)2 * EE * 4);
    // zero zone (one memset): counts, fill, wacc buckets (2*256), 5 stat arrays
    const size_t ZCOUNT = 100000 + 100000 + 512 + 5 * 128;
    int* zz = (int*)alloc(ZCOUNT * 4);
    int* counts = zz;
    int* fill   = zz + 100000;
    float* wacc = (float*)(zz + 200000);     // [2][16] buckets, 16-float stride
    float* sA   = (float*)(zz + 200512);
    float* sB   = sA + 128;
    float* ssA  = sB + 128;
    float* ssB  = ssA + 128;
    float* sAB  = ssB + 128;

    (void)in_sizes; (void)n_in; (void)out_size; (void)ws_size;

    hipMemsetAsync(zz, 0, ZCOUNT * 4, stream);

    const int CHUNKS = (2 * EE + 1023) / 1024;   // 1172
    prep_k<<<264 + CHUNKS * 8, 256, 0, stream>>>(W_a, W_p, k_W, lin_W, edge_ap, edge_pp,
                                                 Wt_a, Wt_p, kWt, linWt, counts);

    const int GB = (NN + 63) / 64;          // 782
    gemm2_k<<<2 * GB, 256, 0, stream>>>(x_a, x_p, Wt_a, Wt_p, b_a, b_p,
                                        att_src_ap, att_dst_ap, att_src_pp, att_dst_pp,
                                        h_a, h_p, as_ap, ad_ap, as_pp, ad_pp, GB);

    const int SB = 392;                     // ceil(100352/256)
    scan1_k<<<SB, 256, 0, stream>>>(counts, incl, bsum);
    scan2_k<<<1, 512, 0, stream>>>(bsum, SB);
    scan3_k<<<SB, 256, 0, stream>>>(incl, bsum, rp_all);

    scat_k<<<CHUNKS * 8, 256, 0, stream>>>(edge_ap, edge_pp, rp_all, fill, csr_all);

    agg4_k<<<2 * NN / 16, 256, 0, stream>>>(h_a, h_p, as_ap, ad_ap, as_pp, ad_pp,
                                            rp_all, csr_all, out_ap, out_pp);

    semstats2_k<<<256 + 2 * GB, 256, 0, stream>>>(out_ap, out_pp, kWt, k_b, q, wacc,
                                                  sA, sB, ssA, ssB, sAB, GB);

    final2_k<<<GB, 256, 0, stream>>>(out_ap, out_pp, wacc, sA, sB, ssA, ssB, sAB,
                                     norm_ms, norm_w, norm_b, linWt, lin_b, out);
}

// Round 11
// 376.723 us; speedup vs baseline: 1.1100x; 1.1100x over previous
//
#include <hip/hip_runtime.h>
#include <math.h>

#define NN   50000
#define EE   600000
#define CCH  128
#define HH   8
#define DD   16
#define OUTC 16
#define NEG  0.2f
#define EPSN 1e-5f
#define SLICE_DIV 12500   // 2*NN / 8 slices
#define CHUNKS 1172       // ceil(2*EE/1024)

typedef _Float16 f16x8 __attribute__((ext_vector_type(8)));
typedef float    f32x4 __attribute__((ext_vector_type(4)));

__device__ __forceinline__ float fast_tanh(float x) {
    x = fminf(10.f, fmaxf(-10.f, x));
    float e = __expf(2.f * x);
    return (e - 1.f) / (e + 1.f);
}

// ---------- weight transpose+convert (4 mats) ----------
__global__ __launch_bounds__(256) void convw_k(const float* __restrict__ W_a,
        const float* __restrict__ W_p, const float* __restrict__ k_W,
        const float* __restrict__ lin_W, _Float16* __restrict__ Wt_a,
        _Float16* __restrict__ Wt_p, _Float16* __restrict__ kWt,
        _Float16* __restrict__ linWt)
{
    int id = blockIdx.x * 256 + threadIdx.x;
    if (id < 32768) {
        int k = id >> 7, n = id & 127;
        Wt_a[n * 256 + k] = (_Float16)W_a[id];
    } else if (id < 49152) {
        int i = id - 32768; int k = i >> 7, n = i & 127;
        Wt_p[n * 128 + k] = (_Float16)W_p[i];
    } else if (id < 65536) {
        int i = id - 49152; int k = i >> 7, n = i & 127;
        kWt[n * 128 + k] = (_Float16)k_W[i];
    } else if (id < 67584) {
        int i = id - 65536; int k = i >> 4, n = i & 15;
        linWt[n * 128 + k] = (_Float16)lin_W[i];
    }
}

// ---------- fused: MFMA GEMM (both projections + alpha) AND XCD-sharded histogram ----------
// Blocks [0, 2*GBn): R8-proven LDS BK=32 GEMM (MFMA-pipe-bound).
// Blocks [2*GBn, ...): edge histogram (latency-bound atomics) — co-scheduled on the
// same CUs, different pipes, so hist time hides under GEMM (m114 overlap).
__global__ __launch_bounds__(256) void gemm2h_k(const float* __restrict__ X_a,
        const float* __restrict__ X_p, const _Float16* __restrict__ Wt_a,
        const _Float16* __restrict__ Wt_p, const float* __restrict__ b_a,
        const float* __restrict__ b_p,
        const float* __restrict__ att_s_ap, const float* __restrict__ att_d_ap,
        const float* __restrict__ att_s_pp, const float* __restrict__ att_d_pp,
        _Float16* __restrict__ h_a, _Float16* __restrict__ h_p,
        float* __restrict__ as_ap, float* __restrict__ ad_ap,
        float* __restrict__ as_pp, float* __restrict__ ad_pp,
        const int* __restrict__ ea, const int* __restrict__ ep,
        int* __restrict__ counts, int GBn)
{
    __shared__ _Float16 As[64][40];
    __shared__ _Float16 Bs[128][40];
    const int t = threadIdx.x;
    if ((int)blockIdx.x >= 2 * GBn) {
        // ---- histogram part ----
        int bb = (int)blockIdx.x - 2 * GBn;
        int slice = bb & 7;
        int chunk = bb >> 3;
        int lo = slice * SLICE_DIV, hi = lo + SLICE_DIV;
        int base = chunk * 1024;
#pragma unroll
        for (int it = 0; it < 4; ++it) {
            int e = base + it * 256 + t;
            if (e < EE) {
                int d = ea[EE + e];
                if (d >= lo && d < hi) atomicAdd(&counts[d], 1);
            } else if (e < 2 * EE) {
                int d = NN + ep[e];
                if (d >= lo && d < hi) atomicAdd(&counts[d], 1);
            }
        }
        return;
    }
    const int which = ((int)blockIdx.x >= GBn) ? 1 : 0;
    const float* X = which ? X_p : X_a;
    const _Float16* Wt = which ? Wt_p : Wt_a;
    const float* bias = which ? b_p : b_a;
    _Float16* Y = which ? h_p : h_a;
    const int K = which ? 128 : 256;
    const int r0 = (blockIdx.x - which * GBn) * 64;
    const int lane = t & 63;
    const int wv = t >> 6;
    const int m16 = lane & 15;
    const int kq = lane >> 4;
    f32x4 acc[8];
#pragma unroll
    for (int i = 0; i < 8; ++i) acc[i] = (f32x4){0.f, 0.f, 0.f, 0.f};

    const int ar = t >> 2;
    const int ak = (t & 3) * 8;
    const int br = t >> 1;
    const int bk = (t & 1) * 16;

    for (int kc = 0; kc < K; kc += 32) {
        int row = r0 + ar;
        f16x8 av;
        if (row < NN) {
            const float4* gp = (const float4*)&X[row * K + kc + ak];
            float4 x0 = gp[0], x1 = gp[1];
            av[0] = (_Float16)x0.x; av[1] = (_Float16)x0.y;
            av[2] = (_Float16)x0.z; av[3] = (_Float16)x0.w;
            av[4] = (_Float16)x1.x; av[5] = (_Float16)x1.y;
            av[6] = (_Float16)x1.z; av[7] = (_Float16)x1.w;
        } else {
#pragma unroll
            for (int j = 0; j < 8; ++j) av[j] = (_Float16)0.f;
        }
        *(f16x8*)&As[ar][ak] = av;
        const f16x8* wp = (const f16x8*)&Wt[br * K + kc + bk];
        *(f16x8*)&Bs[br][bk]     = wp[0];
        *(f16x8*)&Bs[br][bk + 8] = wp[1];
        __syncthreads();
        f16x8 af = *(const f16x8*)&As[wv * 16 + m16][kq * 8];
#pragma unroll
        for (int i = 0; i < 8; ++i) {
            f16x8 bf = *(const f16x8*)&Bs[i * 16 + m16][kq * 8];
            acc[i] = __builtin_amdgcn_mfma_f32_16x16x32_f16(af, bf, acc[i], 0, 0, 0);
        }
        __syncthreads();
    }
    const int rbase = r0 + wv * 16 + kq * 4;
#pragma unroll
    for (int i = 0; i < 8; ++i) {
        int col = i * 16 + m16;
        float b = bias[col];
        float hv[4];
#pragma unroll
        for (int rr = 0; rr < 4; ++rr) hv[rr] = acc[i][rr] + b;
#pragma unroll
        for (int rr = 0; rr < 4; ++rr)
            if (rbase + rr < NN) Y[(rbase + rr) * 128 + col] = (_Float16)hv[rr];
        if (which == 0) {
            float av = att_s_ap[i * 16 + m16];
            float p[4];
#pragma unroll
            for (int rr = 0; rr < 4; ++rr) p[rr] = hv[rr] * av;
#pragma unroll
            for (int x = 1; x < 16; x <<= 1)
#pragma unroll
                for (int rr = 0; rr < 4; ++rr) p[rr] += __shfl_xor(p[rr], x, 64);
            if (m16 == 0) {
#pragma unroll
                for (int rr = 0; rr < 4; ++rr)
                    if (rbase + rr < NN) as_ap[(rbase + rr) * 8 + i] = p[rr];
            }
        } else {
            float a1 = att_d_ap[i * 16 + m16];
            float a2 = att_s_pp[i * 16 + m16];
            float a3 = att_d_pp[i * 16 + m16];
            float p1[4], p2[4], p3[4];
#pragma unroll
            for (int rr = 0; rr < 4; ++rr) {
                p1[rr] = hv[rr] * a1; p2[rr] = hv[rr] * a2; p3[rr] = hv[rr] * a3;
            }
#pragma unroll
            for (int x = 1; x < 16; x <<= 1) {
#pragma unroll
                for (int rr = 0; rr < 4; ++rr) {
                    p1[rr] += __shfl_xor(p1[rr], x, 64);
                    p2[rr] += __shfl_xor(p2[rr], x, 64);
                    p3[rr] += __shfl_xor(p3[rr], x, 64);
                }
            }
            if (m16 == 0) {
#pragma unroll
                for (int rr = 0; rr < 4; ++rr) {
                    if (rbase + rr < NN) {
                        ad_ap[(rbase + rr) * 8 + i] = p1[rr];
                        as_pp[(rbase + rr) * 8 + i] = p2[rr];
                        ad_pp[(rbase + rr) * 8 + i] = p3[rr];
                    }
                }
            }
        }
    }
}

// ---------- scans for CSR row pointers (100000 segments) ----------
__global__ __launch_bounds__(256) void scan1_k(const int* __restrict__ counts,
        int* __restrict__ incl, int* __restrict__ bsum) {
    __shared__ int s[256];
    int t = threadIdx.x;
    int i = blockIdx.x * 256 + t;
    int v = (i < 2 * NN) ? counts[i] : 0;
    s[t] = v; __syncthreads();
    for (int off = 1; off < 256; off <<= 1) {
        int x = (t >= off) ? s[t - off] : 0;
        __syncthreads();
        s[t] += x;
        __syncthreads();
    }
    incl[i] = s[t];
    if (t == 255) bsum[blockIdx.x] = s[255];
}

__global__ __launch_bounds__(512) void scan2_k(int* __restrict__ bsum, int nb) {
    __shared__ int s[512];
    int t = threadIdx.x;
    int v = (t < nb) ? bsum[t] : 0;
    s[t] = v; __syncthreads();
    for (int off = 1; off < 512; off <<= 1) {
        int x = (t >= off) ? s[t - off] : 0;
        __syncthreads();
        s[t] += x;
        __syncthreads();
    }
    if (t < nb) bsum[t] = s[t] - v;   // exclusive
}

__global__ __launch_bounds__(256) void scan3_k(const int* __restrict__ incl,
        const int* __restrict__ bexcl, int* __restrict__ rp) {
    int i = blockIdx.x * 256 + threadIdx.x;
    if (i < 2 * NN) rp[i + 1] = incl[i] + bexcl[blockIdx.x];
    if (i == 0) rp[0] = 0;
}

// ---------- XCD-sharded CSR scatter ----------
__global__ __launch_bounds__(256) void scat_k(const int* __restrict__ ea,
        const int* __restrict__ ep, const int* __restrict__ rp,
        int* __restrict__ fill, int* __restrict__ csr)
{
    int bb = blockIdx.x;
    int slice = bb & 7;
    int chunk = bb >> 3;
    int lo = slice * SLICE_DIV, hi = lo + SLICE_DIV;
    int base = chunk * 1024;
#pragma unroll
    for (int it = 0; it < 4; ++it) {
        int e = base + it * 256 + threadIdx.x;
        if (e < EE) {
            int d = ea[EE + e];
            if (d >= lo && d < hi) {
                int pos = rp[d] + atomicAdd(&fill[d], 1);
                csr[pos] = ea[e];
            }
        } else if (e < 2 * EE) {
            int d = NN + ep[e];
            if (d >= lo && d < hi) {
                int pos = rp[d] + atomicAdd(&fill[d], 1);
                csr[pos] = ep[e - EE];
            }
        }
    }
}

// ---------- aggregation: 4 nodes/wave, 16 lanes (f16x8)/node, inline l, unroll x4 ----------
__global__ __launch_bounds__(256) void agg4_k(
        const _Float16* __restrict__ h_a, const _Float16* __restrict__ h_p,
        const float* __restrict__ as_ap, const float* __restrict__ ad_ap,
        const float* __restrict__ as_pp, const float* __restrict__ ad_pp,
        const int* __restrict__ rp, const int* __restrict__ csr,
        _Float16* __restrict__ out_ap, _Float16* __restrict__ out_pp)
{
    int wave = threadIdx.x >> 6;
    int lane = threadIdx.x & 63;
    int q = lane >> 4;                 // node slot within wave
    int sub = lane & 15;               // 8-channel group: c0 = sub*8
    int gnode = blockIdx.x * 16 + wave * 4 + q;
    bool pp = gnode >= NN;
    int n = pp ? gnode - NN : gnode;
    const _Float16* hsrc = pp ? h_p : h_a;
    const float* as = pp ? as_pp : as_ap;
    const float* ad = pp ? ad_pp : ad_ap;
    _Float16* outb = pp ? out_pp : out_ap;
    int h = sub >> 1;                  // head of this channel group
    float adv = ad[n * 8 + h];
    int p = rp[gnode], p1 = rp[gnode + 1];
    float l = 0.f;
    float acc[8] = {0.f, 0.f, 0.f, 0.f, 0.f, 0.f, 0.f, 0.f};
    for (; p + 3 < p1; p += 4) {
        int s0 = csr[p], s1 = csr[p + 1], s2 = csr[p + 2], s3 = csr[p + 3];
        float a0 = as[s0 * 8 + h] + adv;
        float a1 = as[s1 * 8 + h] + adv;
        float a2 = as[s2 * 8 + h] + adv;
        float a3 = as[s3 * 8 + h] + adv;
        a0 = (a0 >= 0.f) ? a0 : NEG * a0;
        a1 = (a1 >= 0.f) ? a1 : NEG * a1;
        a2 = (a2 >= 0.f) ? a2 : NEG * a2;
        a3 = (a3 >= 0.f) ? a3 : NEG * a3;
        float w0 = __expf(a0), w1 = __expf(a1), w2 = __expf(a2), w3 = __expf(a3);
        f16x8 v0 = *(const f16x8*)&hsrc[s0 * CCH + sub * 8];
        f16x8 v1 = *(const f16x8*)&hsrc[s1 * CCH + sub * 8];
        f16x8 v2 = *(const f16x8*)&hsrc[s2 * CCH + sub * 8];
        f16x8 v3 = *(const f16x8*)&hsrc[s3 * CCH + sub * 8];
        l += (w0 + w1) + (w2 + w3);
#pragma unroll
        for (int i = 0; i < 8; ++i)
            acc[i] += (w0 * (float)v0[i] + w1 * (float)v1[i])
                    + (w2 * (float)v2[i] + w3 * (float)v3[i]);
    }
    for (; p < p1; ++p) {
        int s0 = csr[p];
        float a0 = as[s0 * 8 + h] + adv;
        a0 = (a0 >= 0.f) ? a0 : NEG * a0;
        float w0 = __expf(a0);
        f16x8 v0 = *(const f16x8*)&hsrc[s0 * CCH + sub * 8];
        l += w0;
#pragma unroll
        for (int i = 0; i < 8; ++i) acc[i] += w0 * (float)v0[i];
    }
    float inv = (l > 0.f) ? 1.f / l : 0.f;
    f16x8 o;
#pragma unroll
    for (int i = 0; i < 8; ++i) o[i] = (_Float16)fmaxf(acc[i] * inv, 0.f);
    *(f16x8*)&outb[n * CCH + sub * 8] = o;
}

// ---------- fused: blocks 0..255 channel stats; rest LDS-free sem GEMM ----------
__global__ __launch_bounds__(256) void semstats2_k(const _Float16* __restrict__ Xa,
        const _Float16* __restrict__ Xb, const _Float16* __restrict__ kWt,
        const float* __restrict__ kb, const float* __restrict__ q,
        float* __restrict__ wacc, float* __restrict__ sA, float* __restrict__ sB,
        float* __restrict__ ssA, float* __restrict__ ssB, float* __restrict__ sAB,
        int GBn)
{
    __shared__ float sbuf[640];
    const int t = threadIdx.x;
    if ((int)blockIdx.x < 256) {
        for (int i = t; i < 640; i += 256) sbuf[i] = 0.f;
        __syncthreads();
        int oct = t & 15, rs = t >> 4;
        int start = (int)blockIdx.x * 196;
        int end = start + 196; if (end > NN) end = NN;
        float sa[8] = {0,0,0,0,0,0,0,0}, sb[8] = {0,0,0,0,0,0,0,0};
        float ssa[8] = {0,0,0,0,0,0,0,0}, ssb[8] = {0,0,0,0,0,0,0,0};
        float sab[8] = {0,0,0,0,0,0,0,0};
        for (int r = start + rs; r < end; r += 16) {
            f16x8 va = *(const f16x8*)&Xa[r * 128 + oct * 8];
            f16x8 vb = *(const f16x8*)&Xb[r * 128 + oct * 8];
#pragma unroll
            for (int j = 0; j < 8; ++j) {
                float a = (float)va[j], b = (float)vb[j];
                sa[j] += a; sb[j] += b;
                ssa[j] += a * a; ssb[j] += b * b; sab[j] += a * b;
            }
        }
#pragma unroll
        for (int x = 16; x < 64; x <<= 1) {
#pragma unroll
            for (int j = 0; j < 8; ++j) {
                sa[j]  += __shfl_xor(sa[j],  x, 64);
                sb[j]  += __shfl_xor(sb[j],  x, 64);
                ssa[j] += __shfl_xor(ssa[j], x, 64);
                ssb[j] += __shfl_xor(ssb[j], x, 64);
                sab[j] += __shfl_xor(sab[j], x, 64);
            }
        }
        if ((t & 63) < 16) {
            int c0 = oct * 8;
#pragma unroll
            for (int j = 0; j < 8; ++j) {
                atomicAdd(&sbuf[c0 + j], sa[j]);
                atomicAdd(&sbuf[128 + c0 + j], sb[j]);
                atomicAdd(&sbuf[256 + c0 + j], ssa[j]);
                atomicAdd(&sbuf[384 + c0 + j], ssb[j]);
                atomicAdd(&sbuf[512 + c0 + j], sab[j]);
            }
        }
        __syncthreads();
        if (t < 128) {
            atomicAdd(&sA[t],  sbuf[t]);
            atomicAdd(&sB[t],  sbuf[128 + t]);
            atomicAdd(&ssA[t], sbuf[256 + t]);
            atomicAdd(&ssB[t], sbuf[384 + t]);
            atomicAdd(&sAB[t], sbuf[512 + t]);
        }
    } else {
        const int b = (int)blockIdx.x - 256;
        const int which = (b >= GBn) ? 1 : 0;
        const _Float16* Xh = which ? Xb : Xa;
        const int r0 = (b - which * GBn) * 64;
        const int lane = t & 63, wv = t >> 6;
        const int m16 = lane & 15, kq = lane >> 4;
        const int arow = r0 + wv * 16 + m16;
        f16x8 af[4];
        if (arow < NN) {
#pragma unroll
            for (int kc4 = 0; kc4 < 4; ++kc4)
                af[kc4] = *(const f16x8*)&Xh[arow * 128 + kc4 * 32 + kq * 8];
        } else {
#pragma unroll
            for (int kc4 = 0; kc4 < 4; ++kc4)
#pragma unroll
                for (int j = 0; j < 8; ++j) af[kc4][j] = (_Float16)0.f;
        }
        f32x4 acc[8];
#pragma unroll
        for (int i = 0; i < 8; ++i) acc[i] = (f32x4){0.f, 0.f, 0.f, 0.f};
#pragma unroll
        for (int kc4 = 0; kc4 < 4; ++kc4) {
#pragma unroll
            for (int i = 0; i < 8; ++i) {
                f16x8 bf = *(const f16x8*)&kWt[(i * 16 + m16) * 128 + kc4 * 32 + kq * 8];
                acc[i] = __builtin_amdgcn_mfma_f32_16x16x32_f16(af[kc4], bf, acc[i], 0, 0, 0);
            }
        }
        const int rbase = r0 + wv * 16 + kq * 4;
        float local = 0.f;
#pragma unroll
        for (int i = 0; i < 8; ++i) {
            float kbc = kb[i * 16 + m16], qc = q[i * 16 + m16];
#pragma unroll
            for (int rr = 0; rr < 4; ++rr)
                if (rbase + rr < NN) local += fast_tanh(acc[i][rr] + kbc) * qc;
        }
#pragma unroll
        for (int x = 1; x < 64; x <<= 1) local += __shfl_xor(local, x, 64);
        if (lane == 0) sbuf[wv] = local;
        __syncthreads();
        if (t == 0) {
            float s = sbuf[0] + sbuf[1] + sbuf[2] + sbuf[3];
            atomicAdd(&wacc[which * 256 + (b & 15) * 16], s);
        }
    }
}

// ---------- GraphNorm (inline beta, sums 16 buckets/path) + final 128->16 linear via MFMA ----------
__global__ __launch_bounds__(256) void final2_k(
        const _Float16* __restrict__ oa, const _Float16* __restrict__ ob,
        const float* __restrict__ wacc,
        const float* __restrict__ sA, const float* __restrict__ sB,
        const float* __restrict__ ssA, const float* __restrict__ ssB,
        const float* __restrict__ sAB,
        const float* __restrict__ ms, const float* __restrict__ nw,
        const float* __restrict__ nb,
        const _Float16* __restrict__ linWt, const float* __restrict__ linb,
        float* __restrict__ out)
{
    __shared__ _Float16 As[64][136];
    __shared__ float scl[128], shf[128];
    __shared__ float bcoef[2];
    int t = threadIdx.x;
    if (t < 128) {
        float w0s = 0.f, w1s = 0.f;
#pragma unroll
        for (int i = 0; i < 16; ++i) {
            w0s += wacc[i * 16];
            w1s += wacc[256 + i * 16];
        }
        float w0 = w0s * (1.f / NN), w1 = w1s * (1.f / NN);
        float mm = fmaxf(w0, w1);
        float e0 = __expf(w0 - mm), e1 = __expf(w1 - mm);
        float b0 = e0 / (e0 + e1), b1 = e1 / (e0 + e1);
        if (t == 0) { bcoef[0] = b0; bcoef[1] = b1; }
        int c = t;
        float mean = (b0 * sA[c] + b1 * sB[c]) * (1.f / NN);
        float ex2 = (b0 * b0 * ssA[c] + 2.f * b0 * b1 * sAB[c] + b1 * b1 * ssB[c]) * (1.f / NN);
        float a = mean * ms[c];
        float var = ex2 - 2.f * a * mean + a * a;
        float sc = nw[c] * rsqrtf(var + EPSN);
        scl[c] = sc;
        shf[c] = nb[c] - a * sc;
    }
    __syncthreads();
    float b0 = bcoef[0], b1 = bcoef[1];
    int r0 = blockIdx.x * 64;
    int row = t >> 2, cp = (t & 3) * 32;
    int gr = r0 + row;
    if (gr < NN) {
#pragma unroll
        for (int i = 0; i < 4; ++i) {
            int c0 = cp + i * 8;
            f16x8 va = *(const f16x8*)&oa[gr * CCH + c0];
            f16x8 vb = *(const f16x8*)&ob[gr * CCH + c0];
            f16x8 o;
#pragma unroll
            for (int e2 = 0; e2 < 8; ++e2) {
                float v = b0 * (float)va[e2] + b1 * (float)vb[e2];
                o[e2] = (_Float16)(v * scl[c0 + e2] + shf[c0 + e2]);
            }
            *(f16x8*)&As[row][c0] = o;
        }
    } else {
        f16x8 z;
#pragma unroll
        for (int e2 = 0; e2 < 8; ++e2) z[e2] = (_Float16)0.f;
#pragma unroll
        for (int i = 0; i < 4; ++i) *(f16x8*)&As[row][cp + i * 8] = z;
    }
    __syncthreads();
    int lane = t & 63, wv = t >> 6;
    int m16 = lane & 15, kq = lane >> 4;
    f32x4 acc = (f32x4){0.f, 0.f, 0.f, 0.f};
#pragma unroll
    for (int kc = 0; kc < 128; kc += 32) {
        f16x8 af = *(const f16x8*)&As[wv * 16 + m16][kc + kq * 8];
        f16x8 bf = *(const f16x8*)&linWt[m16 * 128 + kc + kq * 8];
        acc = __builtin_amdgcn_mfma_f32_16x16x32_f16(af, bf, acc, 0, 0, 0);
    }
    float lb = linb[m16];
#pragma unroll
    for (int r = 0; r < 4; ++r) {
        int gr2 = r0 + wv * 16 + kq * 4 + r;
        if (gr2 < NN) out[gr2 * 16 + m16] = acc[r] + lb;
    }
}

extern "C" void kernel_launch(void* const* d_in, const int* in_sizes, int n_in,
                              void* d_out, int out_size, void* d_ws, size_t ws_size,
                              hipStream_t stream) {
    const float* x_a   = (const float*)d_in[0];
    const float* x_p   = (const float*)d_in[1];
    const float* W_a   = (const float*)d_in[2];
    const float* b_a   = (const float*)d_in[3];
    const float* W_p   = (const float*)d_in[4];
    const float* b_p   = (const float*)d_in[5];
    const float* att_src_ap = (const float*)d_in[6];
    const float* att_dst_ap = (const float*)d_in[7];
    const float* att_src_pp = (const float*)d_in[8];
    const float* att_dst_pp = (const float*)d_in[9];
    const float* k_W   = (const float*)d_in[10];
    const float* k_b   = (const float*)d_in[11];
    const float* q     = (const float*)d_in[12];
    const float* norm_w = (const float*)d_in[13];
    const float* norm_b = (const float*)d_in[14];
    const float* norm_ms = (const float*)d_in[15];
    const float* lin_W = (const float*)d_in[16];
    const float* lin_b = (const float*)d_in[17];
    const int* edge_ap = (const int*)d_in[18];
    const int* edge_pp = (const int*)d_in[19];
    float* out = (float*)d_out;

    char* base = (char*)d_ws;
    size_t off = 0;
    auto alloc = [&](size_t bytes) -> void* {
        void* r = base + off;
        off += (bytes + 255) & ~(size_t)255;
        return r;
    };
    _Float16* h_a    = (_Float16*)alloc((size_t)NN * CCH * 2);
    _Float16* h_p    = (_Float16*)alloc((size_t)NN * CCH * 2);
    _Float16* out_ap = (_Float16*)alloc((size_t)NN * CCH * 2);
    _Float16* out_pp = (_Float16*)alloc((size_t)NN * CCH * 2);
    float* as_ap  = (float*)alloc((size_t)NN * HH * 4);
    float* ad_ap  = (float*)alloc((size_t)NN * HH * 4);
    float* as_pp  = (float*)alloc((size_t)NN * HH * 4);
    float* ad_pp  = (float*)alloc((size_t)NN * HH * 4);
    _Float16* Wt_a = (_Float16*)alloc((size_t)128 * 256 * 2);
    _Float16* Wt_p = (_Float16*)alloc((size_t)128 * 128 * 2);
    _Float16* kWt  = (_Float16*)alloc((size_t)128 * 128 * 2);
    _Float16* linWt = (_Float16*)alloc((size_t)16 * 128 * 2);
    int* incl    = (int*)alloc((size_t)100352 * 4);
    int* bsum    = (int*)alloc(512 * 4);
    int* rp_all  = (int*)alloc((size_t)(2 * NN + 1) * 4);
    int* csr_all = (int*)alloc((size_t)2 * EE * 4);
    // zero zone (one memset): counts, fill, wacc buckets (2*256), 5 stat arrays
    const size_t ZCOUNT = 100000 + 100000 + 512 + 5 * 128;
    int* zz = (int*)alloc(ZCOUNT * 4);
    int* counts = zz;
    int* fill   = zz + 100000;
    float* wacc = (float*)(zz + 200000);     // [2][16] buckets, 16-float stride
    float* sA   = (float*)(zz + 200512);
    float* sB   = sA + 128;
    float* ssA  = sB + 128;
    float* ssB  = ssA + 128;
    float* sAB  = ssB + 128;

    (void)in_sizes; (void)n_in; (void)out_size; (void)ws_size;

    hipMemsetAsync(zz, 0, ZCOUNT * 4, stream);

    convw_k<<<264, 256, 0, stream>>>(W_a, W_p, k_W, lin_W, Wt_a, Wt_p, kWt, linWt);

    const int GB = (NN + 63) / 64;          // 782
    gemm2h_k<<<2 * GB + CHUNKS * 8, 256, 0, stream>>>(
        x_a, x_p, Wt_a, Wt_p, b_a, b_p,
        att_src_ap, att_dst_ap, att_src_pp, att_dst_pp,
        h_a, h_p, as_ap, ad_ap, as_pp, ad_pp,
        edge_ap, edge_pp, counts, GB);

    const int SB = 392;                     // ceil(100352/256)
    scan1_k<<<SB, 256, 0, stream>>>(counts, incl, bsum);
    scan2_k<<<1, 512, 0, stream>>>(bsum, SB);
    scan3_k<<<SB, 256, 0, stream>>>(incl, bsum, rp_all);

    scat_k<<<CHUNKS * 8, 256, 0, stream>>>(edge_ap, edge_pp, rp_all, fill, csr_all);

    agg4_k<<<2 * NN / 16, 256, 0, stream>>>(h_a, h_p, as_ap, ad_ap, as_pp, ad_pp,
                                            rp_all, csr_all, out_ap, out_pp);

    semstats2_k<<<256 + 2 * GB, 256, 0, stream>>>(out_ap, out_pp, kWt, k_b, q, wacc,
                                                  sA, sB, ssA, ssB, sAB, GB);

    final2_k<<<GB, 256, 0, stream>>>(out_ap, out_pp, wacc, sA, sB, ssA, ssB, sAB,
                                     norm_ms, norm_w, norm_b, linWt, lin_b, out);
}